// Round 8
// baseline (792.673 us; speedup 1.0000x reference)
//
#include <hip/hip_runtime.h>
#include <cstdint>
#include <cstddef>

#define TOK 16384
#define NE  8192
#define NTILE 32          // 256-code tiles for tilemin
#define WWIN 1e-3f        // rescore window (bound ~2e-4, 5x margin)

// output layout (all float32): loss | z_q(32,64,512) | perp | enc(16384,8192) | idx(16384)
#define O_ZQ   1
#define O_PERP 1048577
#define O_ENC  1048578
#define O_IDX  135266306

typedef short bf16x8 __attribute__((ext_vector_type(8)));
typedef float f32x4  __attribute__((ext_vector_type(4)));

__device__ __forceinline__ unsigned short f2bf(float v) {
  unsigned int u = __float_as_uint(v);
  return (unsigned short)((u + 0x7FFFu + ((u >> 16) & 1u)) >> 16);  // RNE
}

// ---------------------------------------------------------------------------
// K-1: scalar init (se_min_packed)
// ---------------------------------------------------------------------------
__global__ void k_zero(unsigned long long* se_min) {
  if (threadIdx.x == 0) *se_min = ~0ull;
}

// ---------------------------------------------------------------------------
// K0: s_z (numpy 8-acc pairwise, masked), s_e + global (se,idx) packed min,
//     packed=~0, hist=0, tilemin=+inf
// ---------------------------------------------------------------------------
__global__ __launch_bounds__(256) void k_init(
    const float* __restrict__ z, const int* __restrict__ mask,
    const float* __restrict__ emb,
    unsigned long long* __restrict__ packed,
    float* __restrict__ s_z, float* __restrict__ s_e,
    int* __restrict__ hist, unsigned int* __restrict__ tilemin,
    unsigned long long* __restrict__ se_min) {
  int g = blockIdx.x * 256 + threadIdx.x;
  if (g < TOK) {
    int t = g, b = t >> 9, l = t & 511;
    const float* zp = z + (size_t)b * 32768 + l;
    float r[8];
#pragma unroll
    for (int j = 0; j < 8; ++j) { float v = zp[(size_t)j * 512]; r[j] = __fmul_rn(v, v); }
#pragma unroll
    for (int i = 8; i < 64; i += 8)
#pragma unroll
      for (int j = 0; j < 8; ++j) { float v = zp[(size_t)(i + j) * 512]; r[j] = __fadd_rn(r[j], __fmul_rn(v, v)); }
    float s = __fadd_rn(__fadd_rn(__fadd_rn(r[0], r[1]), __fadd_rn(r[2], r[3])),
                        __fadd_rn(__fadd_rn(r[4], r[5]), __fadd_rn(r[6], r[7])));
    s_z[t] = mask[t] ? s : 0.0f;
    packed[t] = ~0ull;
    uint4 inf4 = make_uint4(0x7F800000u, 0x7F800000u, 0x7F800000u, 0x7F800000u);
    uint4* tmi = (uint4*)(tilemin + (size_t)t * NTILE);
#pragma unroll
    for (int i = 0; i < 8; ++i) tmi[i] = inf4;
  } else if (g < TOK + NE) {
    int i = g - TOK;
    const float* ep = emb + (size_t)i * 64;
    float r[8];
#pragma unroll
    for (int j = 0; j < 8; ++j) { float v = ep[j]; r[j] = __fmul_rn(v, v); }
#pragma unroll
    for (int kk = 8; kk < 64; kk += 8)
#pragma unroll
      for (int j = 0; j < 8; ++j) { float v = ep[kk + j]; r[j] = __fadd_rn(r[j], __fmul_rn(v, v)); }
    float s = __fadd_rn(__fadd_rn(__fadd_rn(r[0], r[1]), __fadd_rn(r[2], r[3])),
                        __fadd_rn(__fadd_rn(r[4], r[5]), __fadd_rn(r[6], r[7])));
    s_e[i] = s;
    hist[i] = 0;
    unsigned long long p = ((unsigned long long)__float_as_uint(s) << 32) | (unsigned int)i;
    atomicMin(se_min, p);   // se >= 0 -> plain bits monotone; low32 = lowest idx
  }
}

// ---------------------------------------------------------------------------
// K1: phase A — bf16 MFMA approx distances -> per-(token, 256-code-tile) min.
// Block: 256 thr (4 waves, 2Mx2N), tile 128 tok x 64 codes, K=64 (2 MFMA steps).
// LDS bf16 slot-swizzled (slot ^= row&7). Fused 32KB enc zero-fill per block.
// ---------------------------------------------------------------------------
__global__ __launch_bounds__(256, 2) void k_mfma(
    const float* __restrict__ z, const int* __restrict__ mask,
    const float* __restrict__ emb,
    const float* __restrict__ s_z, const float* __restrict__ s_e,
    unsigned int* __restrict__ tilemin, float* __restrict__ enc_out) {
  __shared__ __align__(16) unsigned short zs[128][64];  // [tok][bf16 k], swizzled 16B slots
  __shared__ __align__(16) unsigned short es[64][64];   // [code][bf16 k]

  const int tid = threadIdx.x;
  const int I0  = blockIdx.x * 64;
  const int T0  = blockIdx.y * 128;
  const int b   = T0 >> 9;
  const int l0  = T0 & 511;

  // ---- stage zs: coalesced fp32 reads along tokens, cvt, b128 swizzled writes
  {
    const int tok = tid & 127, kh = tid >> 7;
    const int mt  = mask[T0 + tok];
    const float* zp = z + (size_t)b * 32768 + l0 + tok;
#pragma unroll
    for (int i = 0; i < 4; ++i) {
      int k0 = kh * 32 + i * 8;
      unsigned int w0 = 0, w1 = 0, w2 = 0, w3 = 0;
      {
        float v0 = mt ? zp[(size_t)(k0 + 0) * 512] : 0.0f;
        float v1 = mt ? zp[(size_t)(k0 + 1) * 512] : 0.0f;
        float v2 = mt ? zp[(size_t)(k0 + 2) * 512] : 0.0f;
        float v3 = mt ? zp[(size_t)(k0 + 3) * 512] : 0.0f;
        float v4 = mt ? zp[(size_t)(k0 + 4) * 512] : 0.0f;
        float v5 = mt ? zp[(size_t)(k0 + 5) * 512] : 0.0f;
        float v6 = mt ? zp[(size_t)(k0 + 6) * 512] : 0.0f;
        float v7 = mt ? zp[(size_t)(k0 + 7) * 512] : 0.0f;
        w0 = (unsigned int)f2bf(v0) | ((unsigned int)f2bf(v1) << 16);
        w1 = (unsigned int)f2bf(v2) | ((unsigned int)f2bf(v3) << 16);
        w2 = (unsigned int)f2bf(v4) | ((unsigned int)f2bf(v5) << 16);
        w3 = (unsigned int)f2bf(v6) | ((unsigned int)f2bf(v7) << 16);
      }
      int slot = (k0 >> 3) ^ (tok & 7);
      *(uint4*)&zs[tok][slot * 8] = make_uint4(w0, w1, w2, w3);
    }
  }
  // ---- stage es: contiguous float4 reads, cvt, 2 b128 swizzled writes
  {
    const int code = tid >> 2, q = tid & 3;   // 64 codes x 4 quarters of 16 k
    const float* ep = emb + (size_t)(I0 + code) * 64 + q * 16;
    unsigned int w[8];
#pragma unroll
    for (int j = 0; j < 8; ++j)
      w[j] = (unsigned int)f2bf(ep[2 * j]) | ((unsigned int)f2bf(ep[2 * j + 1]) << 16);
    int s0 = (q * 2) ^ (code & 7), s1 = (q * 2 + 1) ^ (code & 7);
    *(uint4*)&es[code][s0 * 8] = make_uint4(w[0], w[1], w[2], w[3]);
    *(uint4*)&es[code][s1 * 8] = make_uint4(w[4], w[5], w[6], w[7]);
  }
  __syncthreads();

  const int l  = tid & 63, w = tid >> 6;
  const int wr = w >> 1, wc = w & 1;
  const int rA = l & 15;     // A row / B col within fragment
  const int kg = l >> 4;     // k-group

  f32x4 acc[4][2];
#pragma unroll
  for (int fr = 0; fr < 4; ++fr)
#pragma unroll
    for (int fc = 0; fc < 2; ++fc)
#pragma unroll
      for (int r = 0; r < 4; ++r) acc[fr][fc][r] = 0.0f;

  float* encb = enc_out + (size_t)T0 * 8192 + I0;

#pragma unroll
  for (int q = 0; q < 2; ++q) {
    bf16x8 af[4], bfv[2];
#pragma unroll
    for (int fr = 0; fr < 4; ++fr) {
      int row  = wr * 64 + fr * 16 + rA;
      int slot = (q * 4 + kg) ^ (row & 7);
      af[fr] = *(const bf16x8*)&zs[row][slot * 8];
    }
#pragma unroll
    for (int fc = 0; fc < 2; ++fc) {
      int crow = wc * 32 + fc * 16 + rA;
      int slot = (q * 4 + kg) ^ (crow & 7);
      bfv[fc] = *(const bf16x8*)&es[crow][slot * 8];
    }
#pragma unroll
    for (int fr = 0; fr < 4; ++fr)
#pragma unroll
      for (int fc = 0; fc < 2; ++fc)
        acc[fr][fc] = __builtin_amdgcn_mfma_f32_16x16x32_bf16(af[fr], bfv[fc], acc[fr][fc], 0, 0, 0);

    // fused enc zero-fill: 4 float4 stores per thread per q (32KB tile total)
#pragma unroll
    for (int it = 0; it < 4; ++it) {
      int id  = (q * 4 + it) * 256 + tid;   // 0..2047
      int row = id >> 4, c4 = id & 15;
      *(float4*)(encb + (size_t)row * 8192 + c4 * 4) = make_float4(0.f, 0.f, 0.f, 0.f);
    }
  }

  // ---- epilogue: d_apx = (sz+se) - 2*acc ; per-row min over 64-code tile;
  //      atomicMin into tilemin[token][256-code tile]
  float se2[2];
#pragma unroll
  for (int fc = 0; fc < 2; ++fc) se2[fc] = s_e[I0 + wc * 32 + fc * 16 + rA];
  const int tslot = blockIdx.x >> 2;   // 256-code tile index

#pragma unroll
  for (int fr = 0; fr < 4; ++fr) {
#pragma unroll
    for (int r = 0; r < 4; ++r) {
      int tok = T0 + wr * 64 + fr * 16 + kg * 4 + r;
      float szv = s_z[tok];
      float d0 = (szv + se2[0]) - 2.0f * acc[fr][0][r];
      float d1 = (szv + se2[1]) - 2.0f * acc[fr][1][r];
      float dm = fminf(d0, d1);
      dm = fminf(dm, __shfl_xor(dm, 1, 64));
      dm = fminf(dm, __shfl_xor(dm, 2, 64));
      dm = fminf(dm, __shfl_xor(dm, 4, 64));
      dm = fminf(dm, __shfl_xor(dm, 8, 64));
      if (rA == 0)
        atomicMin(&tilemin[(size_t)tok * NTILE + tslot], __float_as_uint(dm));
    }
  }
}

// ---------------------------------------------------------------------------
// K2: window — per token: mask0 -> packed = global se-min; mask1 -> thresh
// ---------------------------------------------------------------------------
__global__ __launch_bounds__(256) void k_window(
    const int* __restrict__ mask, const unsigned int* __restrict__ tilemin,
    const unsigned long long* __restrict__ se_min,
    unsigned long long* __restrict__ packed, float* __restrict__ thresh) {
  int t = blockIdx.x * 256 + threadIdx.x;
  if (mask[t]) {
    unsigned int mn = 0xFFFFFFFFu;
    const uint4* tm = (const uint4*)(tilemin + (size_t)t * NTILE);
#pragma unroll
    for (int i = 0; i < 8; ++i) {
      uint4 v = tm[i];
      mn = min(mn, min(min(v.x, v.y), min(v.z, v.w)));
    }
    thresh[t] = __uint_as_float(mn) + WWIN;
  } else {
    packed[t] = *se_min;
    thresh[t] = -1.0f;
  }
}

// ---------------------------------------------------------------------------
// K3: exact rescore of candidate tiles (frozen numerics: sequential fmaf chain,
// fl(fl(sz+se)-fl(2*dot)), packed u64 lowest-index tie-break).
// grid (32 tiles x 8 reps) x 256 thr; wave scans 64 tokens at a time (ballot).
// ---------------------------------------------------------------------------
__global__ __launch_bounds__(256) void k_exact(
    const float* __restrict__ z, const float* __restrict__ emb,
    const float* __restrict__ s_z, const float* __restrict__ s_e,
    const unsigned int* __restrict__ tilemin, const float* __restrict__ thresh,
    unsigned long long* __restrict__ packed) {
  __shared__ float el[256][65];
  const int tile = blockIdx.x;
  const int C0   = tile * 256;
  const int tid  = threadIdx.x, l = tid & 63, w = tid >> 6;

  // stage this tile's 256 emb rows (fp32 exact) into LDS
#pragma unroll
  for (int it = 0; it < 16; ++it) {
    int idx = it * 256 + tid;            // 0..4095 float4 units
    int code = idx >> 4, kq = idx & 15;
    float4 v = *(const float4*)(emb + (size_t)(C0 + code) * 64 + kq * 4);
    el[code][kq * 4 + 0] = v.x;
    el[code][kq * 4 + 1] = v.y;
    el[code][kq * 4 + 2] = v.z;
    el[code][kq * 4 + 3] = v.w;
  }
  __syncthreads();

  const int gw   = blockIdx.y * 4 + w;   // 0..31
  const int base = gw * 512;

  for (int s = 0; s < 8; ++s) {
    int tt = base + s * 64 + l;
    float th = thresh[tt];
    float tf = __uint_as_float(tilemin[(size_t)tt * NTILE + tile]);
    unsigned long long bal = __ballot(tf <= th);
    while (bal) {
      int bit = __ffsll((long long)bal) - 1;
      bal &= bal - 1;
      int t = base + s * 64 + bit;
      float zreg = z[(size_t)(t >> 9) * 32768 + (size_t)l * 512 + (t & 511)];
      float szt  = s_z[t];
      float a0 = 0.f, a1 = 0.f, a2 = 0.f, a3 = 0.f;
      for (int k = 0; k < 64; ++k) {
        float zk = __shfl(zreg, k, 64);
        a0 = fmaf(el[l][k], zk, a0);
        a1 = fmaf(el[l + 64][k], zk, a1);
        a2 = fmaf(el[l + 128][k], zk, a2);
        a3 = fmaf(el[l + 192][k], zk, a3);
      }
      unsigned long long best = ~0ull;
      float av[4] = {a0, a1, a2, a3};
#pragma unroll
      for (int c = 0; c < 4; ++c) {
        int code = C0 + l + 64 * c;
        float d = __fsub_rn(__fadd_rn(szt, s_e[code]), __fmul_rn(2.0f, av[c]));
        unsigned int db = __float_as_uint(d);
        db = ((int)db < 0) ? ~db : (db | 0x80000000u);
        unsigned long long p = ((unsigned long long)db << 32) | (unsigned int)code;
        best = (p < best) ? p : best;
      }
#pragma unroll
      for (int off = 1; off < 64; off <<= 1) {
        unsigned long long q = __shfl_xor(best, off, 64);
        best = (q < best) ? q : best;
      }
      if (l == 0) atomicMin(&packed[t], best);
    }
  }
}

// ---------------------------------------------------------------------------
// K4: per-token finalize — coalesced (block = 64 consecutive tokens, 512 thr)
// ---------------------------------------------------------------------------
__global__ __launch_bounds__(512) void k_finalize(
    const float* __restrict__ z, const int* __restrict__ mask,
    const float* __restrict__ emb,
    const unsigned long long* __restrict__ packed,
    float* __restrict__ out_zq, float* __restrict__ out_enc,
    float* __restrict__ out_idx,
    int* __restrict__ hist, float* __restrict__ token_loss) {
  __shared__ float part[8][64];
  const int T0   = blockIdx.x * 64;
  const int lane = threadIdx.x & 63;
  const int w    = threadIdx.x >> 6;
  const int b    = T0 >> 9;
  const int l0   = T0 & 511;
  const int t    = T0 + lane;

  const int idx = (int)(unsigned int)(packed[t] & 0xFFFFFFFFu);

  const float* zb = z      + (size_t)b * 32768 + l0 + lane;
  float*       qb = out_zq + (size_t)b * 32768 + l0 + lane;

  float sq = 0.0f;
#pragma unroll
  for (int cc = 0; cc < 8; ++cc) {
    int c = w * 8 + cc;
    float zv   = zb[(size_t)c * 512];
    float e    = emb[(size_t)idx * 64 + c];
    float diff = __fsub_rn(e, zv);
    qb[(size_t)c * 512] = __fadd_rn(zv, diff);   // z + (z_q - z), bit-exact STE
    sq = fmaf(diff, diff, sq);
  }
  part[w][lane] = sq;
  __syncthreads();

  if (w == 0) {
    float s = __fadd_rn(
        __fadd_rn(__fadd_rn(part[0][lane], part[1][lane]),
                  __fadd_rn(part[2][lane], part[3][lane])),
        __fadd_rn(__fadd_rn(part[4][lane], part[5][lane]),
                  __fadd_rn(part[6][lane], part[7][lane])));
    token_loss[t] = mask[t] ? s : 0.0f;
    out_idx[t] = (float)idx;
    out_enc[(size_t)t * 8192 + idx] = 1.0f;
    atomicAdd(&hist[idx], 1);
  }
}

// ---------------------------------------------------------------------------
// K5a/K5b: scalar reductions
// ---------------------------------------------------------------------------
__global__ __launch_bounds__(256) void k_partial(
    const float* __restrict__ token_loss, const int* __restrict__ mask,
    const int* __restrict__ hist, float* __restrict__ partials) {
  __shared__ float sf[256], sm[256], sh[256];
  const int bb = blockIdx.x, tid = threadIdx.x;
  int ti = bb * 256 + tid;
  sf[tid] = token_loss[ti];
  sm[tid] = (float)mask[ti];
  float h = 0.f;
  if (tid < 128) {
    float pm = (float)hist[bb * 128 + tid] * (1.0f / 16384.0f);
    h = pm * logf(pm + 1e-10f);
  }
  sh[tid] = h;
  __syncthreads();
  for (int off = 128; off; off >>= 1) {
    if (tid < off) { sf[tid] += sf[tid + off]; sm[tid] += sm[tid + off]; sh[tid] += sh[tid + off]; }
    __syncthreads();
  }
  if (tid == 0) {
    partials[bb]       = sf[0];
    partials[64 + bb]  = sm[0];
    partials[128 + bb] = sh[0];
  }
}

__global__ __launch_bounds__(64) void k_final(
    const float* __restrict__ partials, float* __restrict__ out) {
  int tn = threadIdx.x;
  float lo = partials[tn], mc = partials[64 + tn], en = partials[128 + tn];
#pragma unroll
  for (int off = 32; off; off >>= 1) {
    lo += __shfl_down(lo, off, 64);
    mc += __shfl_down(mc, off, 64);
    en += __shfl_down(en, off, 64);
  }
  if (tn == 0) {
    float denom = mc * 64.0f;
    float el = lo / denom;
    out[0]      = __fadd_rn(el, __fmul_rn(0.25f, el));
    out[O_PERP] = expf(-en);
  }
}

// ---------------------------------------------------------------------------
extern "C" void kernel_launch(void* const* d_in, const int* in_sizes, int n_in,
                              void* d_out, int out_size, void* d_ws, size_t ws_size,
                              hipStream_t stream) {
  const float* z    = (const float*)d_in[0];
  const int*   mask = (const int*)d_in[1];
  const float* emb  = (const float*)d_in[2];
  float* out = (float*)d_out;
  char*  ws  = (char*)d_ws;

  unsigned long long* packed  = (unsigned long long*)ws;           // 128 KB
  float*              s_z     = (float*)(ws + 131072);             // 64 KB
  float*              s_e     = (float*)(ws + 196608);             // 32 KB
  int*                hist    = (int*)(ws + 229376);               // 32 KB
  float*              token_loss = (float*)(ws + 262144);          // 64 KB
  float*              partials   = (float*)(ws + 327680);          // 1 KB
  unsigned long long* se_min  = (unsigned long long*)(ws + 331776);// 8 B
  float*              thresh  = (float*)(ws + 335872);             // 64 KB
  unsigned int*       tilemin = (unsigned int*)(ws + 401408);      // 2 MB

  k_zero<<<1, 64, 0, stream>>>(se_min);
  k_init<<<96, 256, 0, stream>>>(z, mask, emb, packed, s_z, s_e, hist, tilemin, se_min);

  dim3 gm(128, 128, 1);   // x: 8192/64 code tiles, y: 16384/128 token tiles
  k_mfma<<<gm, 256, 0, stream>>>(z, mask, emb, s_z, s_e, tilemin, out + O_ENC);

  k_window<<<64, 256, 0, stream>>>(mask, tilemin, se_min, packed, thresh);

  dim3 ge(32, 8, 1);
  k_exact<<<ge, 256, 0, stream>>>(z, emb, s_z, s_e, tilemin, thresh, packed);

  k_finalize<<<256, 512, 0, stream>>>(z, mask, emb, packed,
                                      out + O_ZQ, out + O_ENC, out + O_IDX,
                                      hist, token_loss);

  k_partial<<<64, 256, 0, stream>>>(token_loss, mask, hist, partials);
  k_final<<<1, 64, 0, stream>>>(partials, out);
}

// Round 9
// 363.069 us; speedup vs baseline: 2.1833x; 2.1833x over previous
//
#include <hip/hip_runtime.h>
#include <cstdint>
#include <cstddef>

#define TOK 16384
#define NE  8192
#define NTILE 32          // 256-code tiles
#define WWIN 1.5e-4f      // rescore window (error bound ~1.5e-5, 10x margin)

// output layout (all float32): loss | z_q(32,64,512) | perp | enc(16384,8192) | idx(16384)
#define O_ZQ   1
#define O_PERP 1048577
#define O_ENC  1048578
#define O_IDX  135266306

typedef short bf16x8 __attribute__((ext_vector_type(8)));
typedef float f32x4  __attribute__((ext_vector_type(4)));

__device__ __forceinline__ unsigned short f2bf(float v) {
  unsigned int u = __float_as_uint(v);
  return (unsigned short)((u + 0x7FFFu + ((u >> 16) & 1u)) >> 16);  // RNE
}

// ---------------------------------------------------------------------------
__global__ void k_zero(unsigned long long* se_min) {
  if (threadIdx.x == 0) *se_min = ~0ull;
}

// ---------------------------------------------------------------------------
// K0: s_z (numpy 8-acc pairwise, masked), zt transpose (masked z, contiguous
// per token), s_e + global (se,idx) packed min, packed=~0, hist=0
// ---------------------------------------------------------------------------
__global__ __launch_bounds__(256) void k_init(
    const float* __restrict__ z, const int* __restrict__ mask,
    const float* __restrict__ emb,
    unsigned long long* __restrict__ packed,
    float* __restrict__ s_z, float* __restrict__ s_e,
    int* __restrict__ hist, float* __restrict__ zt,
    unsigned long long* __restrict__ se_min) {
  int g = blockIdx.x * 256 + threadIdx.x;
  if (g < TOK) {
    int t = g, b = t >> 9, l = t & 511;
    const float* zp = z + (size_t)b * 32768 + l;
    const int mt = mask[t];
    float* ztp = zt + (size_t)t * 64;
    float r[8];
#pragma unroll
    for (int j = 0; j < 8; ++j) {
      float v = mt ? zp[(size_t)j * 512] : 0.0f;
      ztp[j] = v;
      r[j] = __fmul_rn(v, v);
    }
#pragma unroll
    for (int i = 8; i < 64; i += 8)
#pragma unroll
      for (int j = 0; j < 8; ++j) {
        float v = mt ? zp[(size_t)(i + j) * 512] : 0.0f;
        ztp[i + j] = v;
        r[j] = __fadd_rn(r[j], __fmul_rn(v, v));
      }
    float s = __fadd_rn(__fadd_rn(__fadd_rn(r[0], r[1]), __fadd_rn(r[2], r[3])),
                        __fadd_rn(__fadd_rn(r[4], r[5]), __fadd_rn(r[6], r[7])));
    s_z[t] = s;   // masked z -> already 0 contribution when mt==0
    packed[t] = ~0ull;
  } else if (g < TOK + NE) {
    int i = g - TOK;
    const float* ep = emb + (size_t)i * 64;
    float r[8];
#pragma unroll
    for (int j = 0; j < 8; ++j) { float v = ep[j]; r[j] = __fmul_rn(v, v); }
#pragma unroll
    for (int kk = 8; kk < 64; kk += 8)
#pragma unroll
      for (int j = 0; j < 8; ++j) { float v = ep[kk + j]; r[j] = __fadd_rn(r[j], __fmul_rn(v, v)); }
    float s = __fadd_rn(__fadd_rn(__fadd_rn(r[0], r[1]), __fadd_rn(r[2], r[3])),
                        __fadd_rn(__fadd_rn(r[4], r[5]), __fadd_rn(r[6], r[7])));
    s_e[i] = s;
    hist[i] = 0;
    unsigned long long p = ((unsigned long long)__float_as_uint(s) << 32) | (unsigned int)i;
    atomicMin(se_min, p);
  }
}

// ---------------------------------------------------------------------------
// K1: phase A — bf16 MFMA approx -> tilemin[t][tile] DIRECT store (one owner
// block per (token,tile); waves combined via LDS atomicMin).
// Block 256 thr (4 waves 2Mx2N), tile 128 tok x 256 codes, K=64.
// Fused 128KB enc zero-fill per block.
// ---------------------------------------------------------------------------
__global__ __launch_bounds__(256, 1) void k_mfma(
    const float* __restrict__ z, const int* __restrict__ mask,
    const float* __restrict__ emb,
    const float* __restrict__ s_z, const float* __restrict__ s_e,
    unsigned int* __restrict__ tilemin, float* __restrict__ enc_out) {
  __shared__ __align__(16) unsigned short zs[128][64];  // [tok][bf16 k], 16B-slot swizzled
  __shared__ __align__(16) unsigned short es[256][64];  // [code][bf16 k]
  __shared__ unsigned int tmins[128];

  const int tid   = threadIdx.x;
  const int tslot = blockIdx.x;        // 0..31 (256-code tile)
  const int I0    = tslot * 256;
  const int T0    = blockIdx.y * 128;
  const int b     = T0 >> 9;
  const int l0    = T0 & 511;

  // ---- stage zs (coalesced fp32 reads along tokens, swizzled b128 writes)
  {
    const int tok = tid & 127, kh = tid >> 7;
    const int mt  = mask[T0 + tok];
    const float* zp = z + (size_t)b * 32768 + l0 + tok;
#pragma unroll
    for (int i = 0; i < 4; ++i) {
      int k0 = kh * 32 + i * 8;
      float v0 = mt ? zp[(size_t)(k0 + 0) * 512] : 0.0f;
      float v1 = mt ? zp[(size_t)(k0 + 1) * 512] : 0.0f;
      float v2 = mt ? zp[(size_t)(k0 + 2) * 512] : 0.0f;
      float v3 = mt ? zp[(size_t)(k0 + 3) * 512] : 0.0f;
      float v4 = mt ? zp[(size_t)(k0 + 4) * 512] : 0.0f;
      float v5 = mt ? zp[(size_t)(k0 + 5) * 512] : 0.0f;
      float v6 = mt ? zp[(size_t)(k0 + 6) * 512] : 0.0f;
      float v7 = mt ? zp[(size_t)(k0 + 7) * 512] : 0.0f;
      unsigned int w0 = (unsigned int)f2bf(v0) | ((unsigned int)f2bf(v1) << 16);
      unsigned int w1 = (unsigned int)f2bf(v2) | ((unsigned int)f2bf(v3) << 16);
      unsigned int w2 = (unsigned int)f2bf(v4) | ((unsigned int)f2bf(v5) << 16);
      unsigned int w3 = (unsigned int)f2bf(v6) | ((unsigned int)f2bf(v7) << 16);
      int slot = (k0 >> 3) ^ (tok & 7);
      *(uint4*)&zs[tok][slot * 8] = make_uint4(w0, w1, w2, w3);
    }
  }
  // ---- stage es: 256 codes (coalesced float4 reads, swizzled b128 writes)
  {
    const int code_ = tid >> 2, q = tid & 3;
#pragma unroll
    for (int co = 0; co < 4; ++co) {
      int code = co * 64 + code_;
      const float* ep = emb + (size_t)(I0 + code) * 64 + q * 16;
      unsigned int w[8];
#pragma unroll
      for (int j = 0; j < 8; ++j)
        w[j] = (unsigned int)f2bf(ep[2 * j]) | ((unsigned int)f2bf(ep[2 * j + 1]) << 16);
      int s0 = (q * 2) ^ (code & 7), s1 = (q * 2 + 1) ^ (code & 7);
      *(uint4*)&es[code][s0 * 8] = make_uint4(w[0], w[1], w[2], w[3]);
      *(uint4*)&es[code][s1 * 8] = make_uint4(w[4], w[5], w[6], w[7]);
    }
  }
  if (tid < 128) tmins[tid] = 0x7F800000u;
  __syncthreads();

  const int l  = tid & 63, w = tid >> 6;
  const int wr = w >> 1, wc = w & 1;
  const int rA = l & 15;     // fragment row/col index
  const int kg = l >> 4;     // k-group

  f32x4 acc[4][8];
#pragma unroll
  for (int fr = 0; fr < 4; ++fr)
#pragma unroll
    for (int fc = 0; fc < 8; ++fc)
#pragma unroll
      for (int r = 0; r < 4; ++r) acc[fr][fc][r] = 0.0f;

  float* encb = enc_out + (size_t)T0 * 8192 + I0;

#pragma unroll
  for (int q = 0; q < 2; ++q) {
    bf16x8 af[4], bfv[8];
#pragma unroll
    for (int fr = 0; fr < 4; ++fr) {
      int row  = wr * 64 + fr * 16 + rA;
      int slot = (q * 4 + kg) ^ (row & 7);
      af[fr] = *(const bf16x8*)&zs[row][slot * 8];
    }
#pragma unroll
    for (int fc = 0; fc < 8; ++fc) {
      int crow = wc * 128 + fc * 16 + rA;
      int slot = (q * 4 + kg) ^ (crow & 7);
      bfv[fc] = *(const bf16x8*)&es[crow][slot * 8];
    }
#pragma unroll
    for (int fr = 0; fr < 4; ++fr)
#pragma unroll
      for (int fc = 0; fc < 8; ++fc)
        acc[fr][fc] = __builtin_amdgcn_mfma_f32_16x16x32_bf16(af[fr], bfv[fc], acc[fr][fc], 0, 0, 0);

    // fused enc zero-fill: 16 float4/thread/q (128x256 tile = 128 KB total)
#pragma unroll
    for (int it = 0; it < 16; ++it) {
      int id  = q * 4096 + it * 256 + tid;   // 0..8191
      int row = id >> 6, c4 = id & 63;
      *(float4*)(encb + (size_t)row * 8192 + c4 * 4) = make_float4(0.f, 0.f, 0.f, 0.f);
    }
  }

  // ---- epilogue: per-token min over this block's 256 codes
  float sev[8];
#pragma unroll
  for (int fc = 0; fc < 8; ++fc) sev[fc] = s_e[I0 + wc * 128 + fc * 16 + rA];

#pragma unroll
  for (int fr = 0; fr < 4; ++fr) {
#pragma unroll
    for (int r = 0; r < 4; ++r) {
      int tok = wr * 64 + fr * 16 + kg * 4 + r;   // block-local token
      float szv = s_z[T0 + tok];
      float dm = __uint_as_float(0x7F800000u);
#pragma unroll
      for (int fc = 0; fc < 8; ++fc)
        dm = fminf(dm, (szv + sev[fc]) - 2.0f * acc[fr][fc][r]);
      dm = fminf(dm, __shfl_xor(dm, 1, 64));
      dm = fminf(dm, __shfl_xor(dm, 2, 64));
      dm = fminf(dm, __shfl_xor(dm, 4, 64));
      dm = fminf(dm, __shfl_xor(dm, 8, 64));
      if (rA == 0) atomicMin(&tmins[tok], __float_as_uint(dm));
    }
  }
  __syncthreads();
  if (tid < 128)
    tilemin[(size_t)(T0 + tid) * NTILE + tslot] = tmins[tid];
}

// ---------------------------------------------------------------------------
// K2: window — mask0 -> packed = global se-min; mask1 -> thresh = min + W
// ---------------------------------------------------------------------------
__global__ __launch_bounds__(256) void k_window(
    const int* __restrict__ mask, const unsigned int* __restrict__ tilemin,
    const unsigned long long* __restrict__ se_min,
    unsigned long long* __restrict__ packed, float* __restrict__ thresh) {
  int t = blockIdx.x * 256 + threadIdx.x;
  if (mask[t]) {
    unsigned int mn = 0xFFFFFFFFu;
    const uint4* tm = (const uint4*)(tilemin + (size_t)t * NTILE);
#pragma unroll
    for (int i = 0; i < 8; ++i) {
      uint4 v = tm[i];
      mn = min(mn, min(min(v.x, v.y), min(v.z, v.w)));
    }
    thresh[t] = __uint_as_float(mn) + WWIN;
  } else {
    packed[t] = *se_min;
    thresh[t] = -1.0f;
  }
}

// ---------------------------------------------------------------------------
// K3: exact rescore. zt row is wave-uniform (scalar loads, no shfl chain);
// emb tile staged k-major elT[64][260] -> one conflict-free ds_read_b128
// per k gives each lane its 4 codes. Exact sequential-k fmaf chain per code.
// ---------------------------------------------------------------------------
__global__ __launch_bounds__(256, 2) void k_exact(
    const float* __restrict__ zt, const float* __restrict__ emb,
    const float* __restrict__ s_z, const float* __restrict__ s_e,
    const unsigned int* __restrict__ tilemin, const float* __restrict__ thresh,
    unsigned long long* __restrict__ packed) {
  __shared__ __align__(16) float elT[64][260];   // [k][code], rows 16B-aligned
  const int tile = blockIdx.x;
  const int C0   = tile * 256;
  const int tid  = threadIdx.x, l = tid & 63, w = tid >> 6;

  // stage emb tile transposed
#pragma unroll
  for (int pass = 0; pass < 16; ++pass) {
    int gid = pass * 256 + tid;          // 0..4095 float4 units
    int code = gid >> 4, kq = gid & 15;
    float4 v = *(const float4*)(emb + (size_t)(C0 + code) * 64 + kq * 4);
    elT[kq * 4 + 0][code] = v.x;
    elT[kq * 4 + 1][code] = v.y;
    elT[kq * 4 + 2][code] = v.z;
    elT[kq * 4 + 3][code] = v.w;
  }
  __syncthreads();

  const int gw   = blockIdx.y * 4 + w;   // 0..31
  const int base = gw * 512;

  for (int s = 0; s < 8; ++s) {
    int tt = base + s * 64 + l;
    float th = thresh[tt];
    unsigned int tm = tilemin[(size_t)tt * NTILE + tile];
    unsigned long long bal = __ballot(__uint_as_float(tm) <= th);
    while (bal) {
      int bit = __ffsll((long long)bal) - 1;
      bal &= bal - 1;
      int t = base + s * 64 + bit;                  // uniform
      const float* zr = zt + (size_t)t * 64;        // uniform base
      float szt = s_z[t];
      float a0 = 0.f, a1 = 0.f, a2 = 0.f, a3 = 0.f;
#pragma unroll 8
      for (int k = 0; k < 64; ++k) {
        float zk = zr[k];                            // wave-uniform scalar
        float4 e4 = *(const float4*)&elT[k][4 * l];  // conflict-free b128
        a0 = fmaf(e4.x, zk, a0);
        a1 = fmaf(e4.y, zk, a1);
        a2 = fmaf(e4.z, zk, a2);
        a3 = fmaf(e4.w, zk, a3);
      }
      unsigned long long best = ~0ull;
      float av[4] = {a0, a1, a2, a3};
#pragma unroll
      for (int q = 0; q < 4; ++q) {
        int code = C0 + 4 * l + q;
        float d = __fsub_rn(__fadd_rn(szt, s_e[code]), __fmul_rn(2.0f, av[q]));
        unsigned int db = __float_as_uint(d);
        db = ((int)db < 0) ? ~db : (db | 0x80000000u);
        unsigned long long p = ((unsigned long long)db << 32) | (unsigned int)code;
        best = (p < best) ? p : best;
      }
#pragma unroll
      for (int off = 1; off < 64; off <<= 1) {
        unsigned long long q = __shfl_xor(best, off, 64);
        best = (q < best) ? q : best;
      }
      if (l == 0) atomicMin(&packed[t], best);
    }
  }
}

// ---------------------------------------------------------------------------
// K4: per-token finalize — coalesced (block = 64 consecutive tokens, 512 thr)
// ---------------------------------------------------------------------------
__global__ __launch_bounds__(512) void k_finalize(
    const float* __restrict__ z, const int* __restrict__ mask,
    const float* __restrict__ emb,
    const unsigned long long* __restrict__ packed,
    float* __restrict__ out_zq, float* __restrict__ out_enc,
    float* __restrict__ out_idx,
    int* __restrict__ hist, float* __restrict__ token_loss) {
  __shared__ float part[8][64];
  const int T0   = blockIdx.x * 64;
  const int lane = threadIdx.x & 63;
  const int w    = threadIdx.x >> 6;
  const int b    = T0 >> 9;
  const int l0   = T0 & 511;
  const int t    = T0 + lane;

  const int idx = (int)(unsigned int)(packed[t] & 0xFFFFFFFFu);

  const float* zb = z      + (size_t)b * 32768 + l0 + lane;
  float*       qb = out_zq + (size_t)b * 32768 + l0 + lane;

  float sq = 0.0f;
#pragma unroll
  for (int cc = 0; cc < 8; ++cc) {
    int c = w * 8 + cc;
    float zv   = zb[(size_t)c * 512];
    float e    = emb[(size_t)idx * 64 + c];
    float diff = __fsub_rn(e, zv);
    qb[(size_t)c * 512] = __fadd_rn(zv, diff);   // z + (z_q - z), bit-exact STE
    sq = fmaf(diff, diff, sq);
  }
  part[w][lane] = sq;
  __syncthreads();

  if (w == 0) {
    float s = __fadd_rn(
        __fadd_rn(__fadd_rn(part[0][lane], part[1][lane]),
                  __fadd_rn(part[2][lane], part[3][lane])),
        __fadd_rn(__fadd_rn(part[4][lane], part[5][lane]),
                  __fadd_rn(part[6][lane], part[7][lane])));
    token_loss[t] = mask[t] ? s : 0.0f;
    out_idx[t] = (float)idx;
    out_enc[(size_t)t * 8192 + idx] = 1.0f;
    atomicAdd(&hist[idx], 1);
  }
}

// ---------------------------------------------------------------------------
// K5a/K5b: scalar reductions
// ---------------------------------------------------------------------------
__global__ __launch_bounds__(256) void k_partial(
    const float* __restrict__ token_loss, const int* __restrict__ mask,
    const int* __restrict__ hist, float* __restrict__ partials) {
  __shared__ float sf[256], sm[256], sh[256];
  const int bb = blockIdx.x, tid = threadIdx.x;
  int ti = bb * 256 + tid;
  sf[tid] = token_loss[ti];
  sm[tid] = (float)mask[ti];
  float h = 0.f;
  if (tid < 128) {
    float pm = (float)hist[bb * 128 + tid] * (1.0f / 16384.0f);
    h = pm * logf(pm + 1e-10f);
  }
  sh[tid] = h;
  __syncthreads();
  for (int off = 128; off; off >>= 1) {
    if (tid < off) { sf[tid] += sf[tid + off]; sm[tid] += sm[tid + off]; sh[tid] += sh[tid + off]; }
    __syncthreads();
  }
  if (tid == 0) {
    partials[bb]       = sf[0];
    partials[64 + bb]  = sm[0];
    partials[128 + bb] = sh[0];
  }
}

__global__ __launch_bounds__(64) void k_final(
    const float* __restrict__ partials, float* __restrict__ out) {
  int tn = threadIdx.x;
  float lo = partials[tn], mc = partials[64 + tn], en = partials[128 + tn];
#pragma unroll
  for (int off = 32; off; off >>= 1) {
    lo += __shfl_down(lo, off, 64);
    mc += __shfl_down(mc, off, 64);
    en += __shfl_down(en, off, 64);
  }
  if (tn == 0) {
    float denom = mc * 64.0f;
    float el = lo / denom;
    out[0]      = __fadd_rn(el, __fmul_rn(0.25f, el));
    out[O_PERP] = expf(-en);
  }
}

// ---------------------------------------------------------------------------
extern "C" void kernel_launch(void* const* d_in, const int* in_sizes, int n_in,
                              void* d_out, int out_size, void* d_ws, size_t ws_size,
                              hipStream_t stream) {
  const float* z    = (const float*)d_in[0];
  const int*   mask = (const int*)d_in[1];
  const float* emb  = (const float*)d_in[2];
  float* out = (float*)d_out;
  char*  ws  = (char*)d_ws;

  unsigned long long* packed  = (unsigned long long*)ws;           // 128 KB
  float*              s_z     = (float*)(ws + 131072);             // 64 KB
  float*              s_e     = (float*)(ws + 196608);             // 32 KB
  int*                hist    = (int*)(ws + 229376);               // 32 KB
  float*              token_loss = (float*)(ws + 262144);          // 64 KB
  float*              partials   = (float*)(ws + 327680);          // 1 KB
  unsigned long long* se_min  = (unsigned long long*)(ws + 331776);// 8 B
  float*              thresh  = (float*)(ws + 335872);             // 64 KB
  unsigned int*       tilemin = (unsigned int*)(ws + 401408);      // 2 MB
  float*              zt      = (float*)(ws + 2498560);            // 4 MB

  k_zero<<<1, 64, 0, stream>>>(se_min);
  k_init<<<96, 256, 0, stream>>>(z, mask, emb, packed, s_z, s_e, hist, zt, se_min);

  dim3 gm(32, 128, 1);   // x: 256-code tiles, y: 128-token tiles
  k_mfma<<<gm, 256, 0, stream>>>(z, mask, emb, s_z, s_e, tilemin, out + O_ENC);

  k_window<<<64, 256, 0, stream>>>(mask, tilemin, se_min, packed, thresh);

  dim3 ge(32, 8, 1);
  k_exact<<<ge, 256, 0, stream>>>(zt, emb, s_z, s_e, tilemin, thresh, packed);

  k_finalize<<<256, 512, 0, stream>>>(z, mask, emb, packed,
                                      out + O_ZQ, out + O_ENC, out + O_IDX,
                                      hist, token_loss);

  k_partial<<<64, 256, 0, stream>>>(token_loss, mask, hist, partials);
  k_final<<<1, 64, 0, stream>>>(partials, out);
}